// Round 10
// baseline (1874.006 us; speedup 1.0000x reference)
//
#include <hip/hip_runtime.h>
#include <hip/hip_bf16.h>

// LightGCN on MI355X: 3x SpMM (COO -> CSR built in-launch) + running sum.
// N_NODES=150000, DIM=64, NNZ=4M.
// R5: fill_k 281us, 370MB HBM write churn (8M random 4B stores).
// R7: int2-packed fill: WRITE 370->247MB (=1 line/edge floor) but dur FLAT
//     -> fill is random-line-op bound, not write-BW bound. bf16 h: spmm
//     only -8%: line-op bound too (2 lines/edge regardless of dtype).
// R9: two-pass stream-bucketed scatter: passB appends edges to 586
//     per-bucket streams (sequential frontiers, L2 write-combining);
//     passC = one block per bucket, places edges at exact CSR slots
//     within an L2-resident 55KB window. Random-line churn eliminated.

#define NUSERS 100000
#define NITEMS 50000
#define NNODES 150000
#define DIM    64
#define NNZ_E  4000000
#define NBKT   ((NNODES + 255) / 256)   // 586 row-buckets of 256 rows

__device__ inline unsigned short f2b(float f) {
    __hip_bfloat16 h = __float2bfloat16(f);   // RN
    return *reinterpret_cast<unsigned short*>(&h);
}
__device__ inline float b2f(unsigned short b) {
    return __uint_as_float((unsigned)b << 16);
}

// ---- CSR row offsets ----------------------------------------------------

__global__ void hist_k(const int* __restrict__ rows, int* __restrict__ deg) {
    int i = blockIdx.x * 256 + threadIdx.x;
    if (i < NNZ_E) atomicAdd(&deg[rows[i]], 1);
}

__global__ void scan_block_k(const int* __restrict__ deg, int* __restrict__ rs,
                             int* __restrict__ bsum) {
    __shared__ int s[256];
    int t = threadIdx.x;
    int i = blockIdx.x * 256 + t;
    int v = (i < NNODES) ? deg[i] : 0;
    s[t] = v;
    __syncthreads();
    for (int off = 1; off < 256; off <<= 1) {
        int add = (t >= off) ? s[t - off] : 0;
        __syncthreads();
        s[t] += add;
        __syncthreads();
    }
    if (i < NNODES) rs[i] = s[t] - v;          // exclusive within block
    if (t == 255) bsum[blockIdx.x] = s[255];   // block total
}

__global__ void scan_bsum_k(int* __restrict__ bsum, int nb) {
    __shared__ int s[1024];
    int t = threadIdx.x;
    int v = (t < nb) ? bsum[t] : 0;
    s[t] = v;
    __syncthreads();
    for (int off = 1; off < 1024; off <<= 1) {
        int add = (t >= off) ? s[t - off] : 0;
        __syncthreads();
        s[t] += add;
        __syncthreads();
    }
    if (t < nb) bsum[t] = s[t] - v;
}

__global__ void finalize_k(int* __restrict__ rs, const int* __restrict__ bsum,
                           int* __restrict__ cursor) {
    int i = blockIdx.x * 256 + threadIdx.x;
    if (i < NNODES) {
        int v = rs[i] + bsum[blockIdx.x];
        rs[i] = v;
        cursor[i] = v;
    }
    if (i == 0) rs[NNODES] = NNZ_E;
}

// ---- two-pass bucketed edge placement -----------------------------------

// bucket write cursors start at the bucket's CSR base (free from rs)
__global__ void bcur_init_k(const int* __restrict__ rs, int* __restrict__ bcur) {
    int b = blockIdx.x * 256 + threadIdx.x;
    if (b < NBKT) bcur[b] = rs[b * 256];
}

// passB: append each edge to its row-bucket's stream. 586 sequential write
// frontiers (37KB active footprint) instead of 4M random lines.
// pack: col in bits 0..17 (150000 < 2^18), row&255 in bits 18..25.
__global__ void passB_k(const int* __restrict__ rows, const int* __restrict__ cols,
                        const float* __restrict__ vals, int* __restrict__ bcur,
                        int2* __restrict__ ebuf) {
    int i = blockIdx.x * 256 + threadIdx.x;
    if (i < NNZ_E) {
        int r = rows[i];
        int p = atomicAdd(&bcur[r >> 8], 1);
        ebuf[p] = make_int2(cols[i] | ((r & 255) << 18), __float_as_int(vals[i]));
    }
}

// passC: one block per bucket -> bucket's ~55KB cedge window written by a
// single CU (local-L2 write combining). Exact CSR slot via per-row cursor.
__global__ void passC_k(const int* __restrict__ rs, const int2* __restrict__ ebuf,
                        int* __restrict__ cursor, int2* __restrict__ cedge) {
    int b = blockIdx.x;
    int s = rs[b * 256];
    int e = rs[min((b + 1) * 256, NNODES)];
    for (int j = s + threadIdx.x; j < e; j += blockDim.x) {
        int2 ee = ebuf[j];
        int row = (b << 8) | ((unsigned)ee.x >> 18);
        int col = ee.x & 0x3FFFF;
        int p = atomicAdd(&cursor[row], 1);
        cedge[p] = make_int2(col, ee.y);
    }
}

// ---- dense init: h0(bf16) = all_emb; esum(fp32, = d_out) = all_emb ------

__global__ void init_k(const float4* __restrict__ ue, const float4* __restrict__ ie,
                       ushort4* __restrict__ h0, float4* __restrict__ esum) {
    int i = blockIdx.x * 256 + threadIdx.x;
    const int NU4 = NUSERS * (DIM / 4);   // 1,600,000
    const int NT4 = NNODES * (DIM / 4);   // 2,400,000
    if (i < NT4) {
        float4 v = (i < NU4) ? ue[i] : ie[i - NU4];
        esum[i] = v;
        ushort4 b;
        b.x = f2b(v.x); b.y = f2b(v.y); b.z = f2b(v.z); b.w = f2b(v.w);
        h0[i] = b;
    }
}

// ---- SpMM: one wave per row, lane = dim; x/hout bf16, esum fp32 ---------

template <int FINAL>
__global__ void spmm_k(const int* __restrict__ rs, const int2* __restrict__ cedge,
                       const unsigned short* __restrict__ x,
                       unsigned short* __restrict__ hout, float* __restrict__ esum) {
    int w    = (blockIdx.x * blockDim.x + threadIdx.x) >> 6;  // row id
    int lane = threadIdx.x & 63;                              // dim id
    if (w >= NNODES) return;
    int s = rs[w], e = rs[w + 1];
    float acc = 0.f;
    int j = s;
    // 4-wide unroll: 4 independent coalesced 128B gathers in flight
    for (; j + 4 <= e; j += 4) {
        int2 e0 = cedge[j],     e1 = cedge[j + 1];
        int2 e2 = cedge[j + 2], e3 = cedge[j + 3];
        float x0 = b2f(x[e0.x * DIM + lane]);
        float x1 = b2f(x[e1.x * DIM + lane]);
        float x2 = b2f(x[e2.x * DIM + lane]);
        float x3 = b2f(x[e3.x * DIM + lane]);
        acc = fmaf(__int_as_float(e0.y), x0, acc);
        acc = fmaf(__int_as_float(e1.y), x1, acc);
        acc = fmaf(__int_as_float(e2.y), x2, acc);
        acc = fmaf(__int_as_float(e3.y), x3, acc);
    }
    for (; j < e; ++j) {
        int2 ee = cedge[j];
        acc = fmaf(__int_as_float(ee.y), b2f(x[ee.x * DIM + lane]), acc);
    }

    int o = w * DIM + lane;
    float r = esum[o] + acc;
    if (FINAL) {
        esum[o] = r * 0.25f;   // esum IS d_out
    } else {
        esum[o] = r;
        hout[o] = f2b(acc);
    }
}

// ---- launch -------------------------------------------------------------

extern "C" void kernel_launch(void* const* d_in, const int* in_sizes, int n_in,
                              void* d_out, int out_size, void* d_ws, size_t ws_size,
                              hipStream_t stream) {
    const float* ue   = (const float*)d_in[0];
    const float* ie   = (const float*)d_in[1];
    const float* vals = (const float*)d_in[2];
    const int*   rows = (const int*)d_in[3];
    const int*   cols = (const int*)d_in[4];
    float*       out  = (float*)d_out;   // doubles as emb_sum accumulator

    char*  ws  = (char*)d_ws;
    size_t off = 0;
    auto alloc = [&](size_t bytes) -> char* {
        char* p = ws + off;
        off += (bytes + 255) & ~size_t(255);
        return p;
    };
    unsigned short* h0 = (unsigned short*)alloc((size_t)NNODES * DIM * 2);  // 19.2 MB
    unsigned short* h1 = (unsigned short*)alloc((size_t)NNODES * DIM * 2);  // 19.2 MB
    int2*  cedge  = (int2*)alloc((size_t)NNZ_E * 8);                        // 32 MB
    int2*  ebuf   = (int2*)alloc((size_t)NNZ_E * 8);                        // 32 MB
    int*   deg    = (int*)alloc((size_t)NNODES * 4);
    int*   rs     = (int*)alloc((size_t)(NNODES + 1) * 4);
    int*   cursor = (int*)alloc((size_t)NNODES * 4);
    int*   bcur   = (int*)alloc((size_t)NBKT * 4);
    int*   bsum   = (int*)alloc(1024 * 4);
    (void)in_sizes; (void)n_in; (void)out_size;

    // Workspace guard: insufficient ws -> launch nothing (clean absmax fail,
    // not an OOB fault).
    if (ws_size < off) return;

    // CSR row offsets
    hipMemsetAsync(deg, 0, (size_t)NNODES * 4, stream);
    hist_k<<<(NNZ_E + 255) / 256, 256, 0, stream>>>(rows, deg);
    const int NB = (NNODES + 255) / 256;  // 586
    scan_block_k<<<NB, 256, 0, stream>>>(deg, rs, bsum);
    scan_bsum_k<<<1, 1024, 0, stream>>>(bsum, NB);
    finalize_k<<<NB, 256, 0, stream>>>(rs, bsum, cursor);

    // bucketed two-pass edge placement (replaces random-scatter fill_k)
    bcur_init_k<<<(NBKT + 255) / 256, 256, 0, stream>>>(rs, bcur);
    passB_k<<<(NNZ_E + 255) / 256, 256, 0, stream>>>(rows, cols, vals, bcur, ebuf);
    passC_k<<<NBKT, 256, 0, stream>>>(rs, ebuf, cursor, cedge);

    // dense init: h0(bf16) = all_emb, out(fp32 esum) = all_emb
    init_k<<<(NNODES * (DIM / 4) + 255) / 256, 256, 0, stream>>>(
        (const float4*)ue, (const float4*)ie, (ushort4*)h0, (float4*)out);

    // 3 propagation layers, emb_sum fused; last layer fuses /4
    const int SG = (NNODES * 64) / 256;  // 37500 blocks, 4 waves (rows) each
    spmm_k<0><<<SG, 256, 0, stream>>>(rs, cedge, h0, h1, out);
    spmm_k<0><<<SG, 256, 0, stream>>>(rs, cedge, h1, h0, out);
    spmm_k<1><<<SG, 256, 0, stream>>>(rs, cedge, h0, h1, out);
}

// Round 11
// 840.051 us; speedup vs baseline: 2.2308x; 2.2308x over previous
//
#include <hip/hip_runtime.h>
#include <hip/hip_bf16.h>

// LightGCN on MI355X: 3x SpMM + running sum. N=150000, DIM=64, NNZ=4M.
// R5:  fill_k 281us (random 4B scatter, 370MB write churn).
// R7:  int2 pack: WRITE->247MB (1 line/edge floor) but dur FLAT -> line-op
//      bound (~14G random lines/s). bf16 h: spmm only -8% (2 lines/edge
//      regardless of dtype).
// R9:  586-counter passB = 1102us: 4M atomics / 586 addrs = 6830-deep
//      contended chains x ~160ns = the whole time. Lesson: scatter cost =
//      max(line-op floor, per-address atomic chain).
// R10: LDS-aggregated multisplit (radix-style):
//      bhist (LDS hist, 64x293 global atomics) -> bscan -> pass1 (per-block
//      LDS hist + ONE atomic/(block,bucket), 123-deep chains; ~112-edge
//      contiguous runs) -> passC (per-bucket LDS rank, writes exact CSR
//      slots in L2-resident 110KB window AND emits rs directly).
//      hist_k + 3 scan kernels + fill_k all eliminated.

#define NUSERS 100000
#define NITEMS 50000
#define NNODES 150000
#define DIM    64
#define NNZ_E  4000000
#define BSH    9                          // bucket = row >> 9 (512 rows)
#define NBKT   ((NNODES + 511) / 512)     // 293
#define CHUNK  32768                      // edges per pass1 block
#define NB1    ((NNZ_E + CHUNK - 1) / CHUNK)  // 123

__device__ inline unsigned short f2b(float f) {
    __hip_bfloat16 h = __float2bfloat16(f);
    return *reinterpret_cast<unsigned short*>(&h);
}
__device__ inline float b2f(unsigned short b) {
    return __uint_as_float((unsigned)b << 16);
}

// ---- bucket histogram (LDS-aggregated) ----------------------------------

__global__ void bhist_k(const int* __restrict__ rows, int* __restrict__ bcnt) {
    __shared__ int cnt[NBKT];
    for (int i = threadIdx.x; i < NBKT; i += 256) cnt[i] = 0;
    __syncthreads();
    int stride = gridDim.x * 256;
    for (int i = blockIdx.x * 256 + threadIdx.x; i < NNZ_E; i += stride)
        atomicAdd(&cnt[rows[i] >> BSH], 1);
    __syncthreads();
    for (int i = threadIdx.x; i < NBKT; i += 256)
        if (cnt[i]) atomicAdd(&bcnt[i], cnt[i]);
}

// ---- exclusive scan of 293 bucket counts (1 block of 512) ---------------

__global__ void bscan_k(const int* __restrict__ bcnt, int* __restrict__ bbase,
                        int* __restrict__ bcur, int* __restrict__ rs) {
    __shared__ int s[512];
    int t = threadIdx.x;
    int v = (t < NBKT) ? bcnt[t] : 0;
    s[t] = v;
    __syncthreads();
    for (int off = 1; off < 512; off <<= 1) {
        int add = (t >= off) ? s[t - off] : 0;
        __syncthreads();
        s[t] += add;
        __syncthreads();
    }
    if (t < NBKT) {
        int ex = s[t] - v;
        bbase[t] = ex;
        bcur[t]  = ex;
    }
    if (t == 0) {
        bbase[NBKT] = NNZ_E;
        rs[NNODES]  = NNZ_E;
    }
}

// ---- pass1: multisplit scatter into bucket-grouped ebuf -----------------
// per block: LDS hist of its 32K-edge chunk -> 1 global atomic per bucket
// -> re-read chunk, place via LDS cursors. Writes land as ~112-edge
// (~900B) contiguous runs per bucket. pack: col bits0-17, localrow bits18-26.

__global__ void pass1_k(const int* __restrict__ rows, const int* __restrict__ cols,
                        const float* __restrict__ vals, int* __restrict__ bcur,
                        int2* __restrict__ ebuf) {
    __shared__ int lcnt[NBKT];
    __shared__ int lcur[NBKT];
    int base = blockIdx.x * CHUNK;
    int end  = min(base + CHUNK, NNZ_E);
    for (int i = threadIdx.x; i < NBKT; i += 256) lcnt[i] = 0;
    __syncthreads();
    for (int i = base + threadIdx.x; i < end; i += 256)
        atomicAdd(&lcnt[rows[i] >> BSH], 1);
    __syncthreads();
    for (int i = threadIdx.x; i < NBKT; i += 256)
        lcur[i] = lcnt[i] ? atomicAdd(&bcur[i], lcnt[i]) : 0;
    __syncthreads();
    for (int i = base + threadIdx.x; i < end; i += 256) {
        int r = rows[i];
        int p = atomicAdd(&lcur[r >> BSH], 1);
        ebuf[p] = make_int2(cols[i] | ((r & 511) << 18), __float_as_int(vals[i]));
    }
}

// ---- passC: per-bucket LDS ranking -> exact CSR slots + rs --------------

__global__ void passC_k(const int* __restrict__ bbase, const int2* __restrict__ ebuf,
                        int* __restrict__ rs, int2* __restrict__ cedge) {
    __shared__ int rcnt[512];
    __shared__ int rbase[512];
    __shared__ int s[256];
    int b  = blockIdx.x;
    int t  = threadIdx.x;
    int s0 = bbase[b], e0 = bbase[b + 1];
    int rows0 = b << BSH;
    int nrows = min(512, NNODES - rows0);

    rcnt[t] = 0; rcnt[t + 256] = 0;
    __syncthreads();
    for (int j = s0 + t; j < e0; j += 256)
        atomicAdd(&rcnt[(unsigned)ebuf[j].x >> 18], 1);
    __syncthreads();

    // exclusive scan of rcnt[512]: pair-serial + HS over 256 pair sums
    int a0 = rcnt[2 * t], a1 = rcnt[2 * t + 1];
    s[t] = a0 + a1;
    __syncthreads();
    for (int off = 1; off < 256; off <<= 1) {
        int add = (t >= off) ? s[t - off] : 0;
        __syncthreads();
        s[t] += add;
        __syncthreads();
    }
    int pbase = s[t] - (a0 + a1);
    rbase[2 * t]     = pbase;
    rbase[2 * t + 1] = pbase + a0;
    __syncthreads();

    // emit rs for this bucket's rows
    if (t < nrows)           rs[rows0 + t]       = s0 + rbase[t];
    if (t + 256 < nrows)     rs[rows0 + t + 256] = s0 + rbase[t + 256];

    // reuse rcnt as running cursors
    rcnt[t] = rbase[t]; rcnt[t + 256] = rbase[t + 256];
    __syncthreads();

    for (int j = s0 + t; j < e0; j += 256) {
        int2 ee = ebuf[j];
        int lr  = (unsigned)ee.x >> 18;
        int pos = s0 + atomicAdd(&rcnt[lr], 1);
        cedge[pos] = make_int2(ee.x & 0x3FFFF, ee.y);
    }
}

// ---- dense init: h0(bf16) = all_emb; esum(fp32, = d_out) = all_emb ------

__global__ void init_k(const float4* __restrict__ ue, const float4* __restrict__ ie,
                       ushort4* __restrict__ h0, float4* __restrict__ esum) {
    int i = blockIdx.x * 256 + threadIdx.x;
    const int NU4 = NUSERS * (DIM / 4);
    const int NT4 = NNODES * (DIM / 4);
    if (i < NT4) {
        float4 v = (i < NU4) ? ue[i] : ie[i - NU4];
        esum[i] = v;
        ushort4 b;
        b.x = f2b(v.x); b.y = f2b(v.y); b.z = f2b(v.z); b.w = f2b(v.w);
        h0[i] = b;
    }
}

// ---- SpMM: one wave per row, lane = dim; x/hout bf16, esum fp32 ---------

template <int FINAL>
__global__ void spmm_k(const int* __restrict__ rs, const int2* __restrict__ cedge,
                       const unsigned short* __restrict__ x,
                       unsigned short* __restrict__ hout, float* __restrict__ esum) {
    int w    = (blockIdx.x * blockDim.x + threadIdx.x) >> 6;
    int lane = threadIdx.x & 63;
    if (w >= NNODES) return;
    int s = rs[w], e = rs[w + 1];
    float acc = 0.f;
    int j = s;
    for (; j + 4 <= e; j += 4) {
        int2 e0 = cedge[j],     e1 = cedge[j + 1];
        int2 e2 = cedge[j + 2], e3 = cedge[j + 3];
        float x0 = b2f(x[e0.x * DIM + lane]);
        float x1 = b2f(x[e1.x * DIM + lane]);
        float x2 = b2f(x[e2.x * DIM + lane]);
        float x3 = b2f(x[e3.x * DIM + lane]);
        acc = fmaf(__int_as_float(e0.y), x0, acc);
        acc = fmaf(__int_as_float(e1.y), x1, acc);
        acc = fmaf(__int_as_float(e2.y), x2, acc);
        acc = fmaf(__int_as_float(e3.y), x3, acc);
    }
    for (; j < e; ++j) {
        int2 ee = cedge[j];
        acc = fmaf(__int_as_float(ee.y), b2f(x[ee.x * DIM + lane]), acc);
    }

    int o = w * DIM + lane;
    float r = esum[o] + acc;
    if (FINAL) {
        esum[o] = r * 0.25f;   // esum IS d_out
    } else {
        esum[o] = r;
        hout[o] = f2b(acc);
    }
}

// ---- launch -------------------------------------------------------------

extern "C" void kernel_launch(void* const* d_in, const int* in_sizes, int n_in,
                              void* d_out, int out_size, void* d_ws, size_t ws_size,
                              hipStream_t stream) {
    const float* ue   = (const float*)d_in[0];
    const float* ie   = (const float*)d_in[1];
    const float* vals = (const float*)d_in[2];
    const int*   rows = (const int*)d_in[3];
    const int*   cols = (const int*)d_in[4];
    float*       out  = (float*)d_out;

    char*  ws  = (char*)d_ws;
    size_t off = 0;
    auto alloc = [&](size_t bytes) -> char* {
        char* p = ws + off;
        off += (bytes + 255) & ~size_t(255);
        return p;
    };
    unsigned short* h0 = (unsigned short*)alloc((size_t)NNODES * DIM * 2);  // 19.2 MB
    unsigned short* h1 = (unsigned short*)alloc((size_t)NNODES * DIM * 2);  // 19.2 MB
    int2*  cedge  = (int2*)alloc((size_t)NNZ_E * 8);                        // 32 MB
    int2*  ebuf   = (int2*)alloc((size_t)NNZ_E * 8);                        // 32 MB
    int*   rs     = (int*)alloc((size_t)(NNODES + 1) * 4);
    int*   bcnt   = (int*)alloc((size_t)(NBKT + 1) * 4);
    int*   bbase  = (int*)alloc((size_t)(NBKT + 1) * 4);
    int*   bcur   = (int*)alloc((size_t)(NBKT + 1) * 4);
    (void)in_sizes; (void)n_in; (void)out_size;

    if (ws_size < off) return;   // clean absmax fail, not OOB fault

    // CSR build: LDS-aggregated multisplit
    hipMemsetAsync(bcnt, 0, (size_t)(NBKT + 1) * 4, stream);
    bhist_k<<<64, 256, 0, stream>>>(rows, bcnt);
    bscan_k<<<1, 512, 0, stream>>>(bcnt, bbase, bcur, rs);
    pass1_k<<<NB1, 256, 0, stream>>>(rows, cols, vals, bcur, ebuf);
    passC_k<<<NBKT, 256, 0, stream>>>(bbase, ebuf, rs, cedge);

    // dense init
    init_k<<<(NNODES * (DIM / 4) + 255) / 256, 256, 0, stream>>>(
        (const float4*)ue, (const float4*)ie, (ushort4*)h0, (float4*)out);

    // 3 propagation layers, emb_sum fused; last fuses /4
    const int SG = (NNODES * 64) / 256;
    spmm_k<0><<<SG, 256, 0, stream>>>(rs, cedge, h0, h1, out);
    spmm_k<0><<<SG, 256, 0, stream>>>(rs, cedge, h1, h0, out);
    spmm_k<1><<<SG, 256, 0, stream>>>(rs, cedge, h0, h1, out);
}

// Round 12
// 678.508 us; speedup vs baseline: 2.7620x; 1.2381x over previous
//
#include <hip/hip_runtime.h>
#include <hip/hip_bf16.h>

// LightGCN on MI355X: 3x SpMM + running sum. N=150000, DIM=64, NNZ=4M.
// R5:  fill_k 281us (random 4B scatter, 370MB write churn).
// R7:  int2 pack: WRITE->247MB (1 line/edge floor) but dur FLAT -> line-op
//      bound. bf16 h: spmm only -8% (2 lines/edge regardless of dtype).
// R9:  586-counter passB = 1102us: 6830-deep contended atomic chains.
// R10: LDS-aggregated multisplit: 1874->840us. pass1 163us top, but
//      OccupancyPercent=5% (123 blocks = grid-starved), VALU 1%, HBM 5%.
// R11: (a) pass1 CHUNK 32768->8192 (489 blocks, 4x parallelism);
//      (b) bhist 64->256 blocks;
//      (c) spmm unroll 4->8 (diagnostic: latency- vs L3-BW-bound; spmm is
//          ~190us x3 = 68% of total, never yet directly profiled).

#define NUSERS 100000
#define NITEMS 50000
#define NNODES 150000
#define DIM    64
#define NNZ_E  4000000
#define BSH    9                          // bucket = row >> 9 (512 rows)
#define NBKT   ((NNODES + 511) / 512)     // 293
#define CHUNK  8192                       // edges per pass1 block
#define NB1    ((NNZ_E + CHUNK - 1) / CHUNK)  // 489

__device__ inline unsigned short f2b(float f) {
    __hip_bfloat16 h = __float2bfloat16(f);
    return *reinterpret_cast<unsigned short*>(&h);
}
__device__ inline float b2f(unsigned short b) {
    return __uint_as_float((unsigned)b << 16);
}

// ---- bucket histogram (LDS-aggregated) ----------------------------------

__global__ void bhist_k(const int* __restrict__ rows, int* __restrict__ bcnt) {
    __shared__ int cnt[NBKT];
    for (int i = threadIdx.x; i < NBKT; i += 256) cnt[i] = 0;
    __syncthreads();
    int stride = gridDim.x * 256;
    for (int i = blockIdx.x * 256 + threadIdx.x; i < NNZ_E; i += stride)
        atomicAdd(&cnt[rows[i] >> BSH], 1);
    __syncthreads();
    for (int i = threadIdx.x; i < NBKT; i += 256)
        if (cnt[i]) atomicAdd(&bcnt[i], cnt[i]);
}

// ---- exclusive scan of 293 bucket counts (1 block of 512) ---------------

__global__ void bscan_k(const int* __restrict__ bcnt, int* __restrict__ bbase,
                        int* __restrict__ bcur, int* __restrict__ rs) {
    __shared__ int s[512];
    int t = threadIdx.x;
    int v = (t < NBKT) ? bcnt[t] : 0;
    s[t] = v;
    __syncthreads();
    for (int off = 1; off < 512; off <<= 1) {
        int add = (t >= off) ? s[t - off] : 0;
        __syncthreads();
        s[t] += add;
        __syncthreads();
    }
    if (t < NBKT) {
        int ex = s[t] - v;
        bbase[t] = ex;
        bcur[t]  = ex;
    }
    if (t == 0) {
        bbase[NBKT] = NNZ_E;
        rs[NNODES]  = NNZ_E;
    }
}

// ---- pass1: multisplit scatter into bucket-grouped ebuf -----------------

__global__ void pass1_k(const int* __restrict__ rows, const int* __restrict__ cols,
                        const float* __restrict__ vals, int* __restrict__ bcur,
                        int2* __restrict__ ebuf) {
    __shared__ int lcnt[NBKT];
    __shared__ int lcur[NBKT];
    int base = blockIdx.x * CHUNK;
    int end  = min(base + CHUNK, NNZ_E);
    for (int i = threadIdx.x; i < NBKT; i += 256) lcnt[i] = 0;
    __syncthreads();
    for (int i = base + threadIdx.x; i < end; i += 256)
        atomicAdd(&lcnt[rows[i] >> BSH], 1);
    __syncthreads();
    for (int i = threadIdx.x; i < NBKT; i += 256)
        lcur[i] = lcnt[i] ? atomicAdd(&bcur[i], lcnt[i]) : 0;
    __syncthreads();
    for (int i = base + threadIdx.x; i < end; i += 256) {
        int r = rows[i];
        int p = atomicAdd(&lcur[r >> BSH], 1);
        ebuf[p] = make_int2(cols[i] | ((r & 511) << 18), __float_as_int(vals[i]));
    }
}

// ---- passC: per-bucket LDS ranking -> exact CSR slots + rs --------------

__global__ void passC_k(const int* __restrict__ bbase, const int2* __restrict__ ebuf,
                        int* __restrict__ rs, int2* __restrict__ cedge) {
    __shared__ int rcnt[512];
    __shared__ int rbase[512];
    __shared__ int s[256];
    int b  = blockIdx.x;
    int t  = threadIdx.x;
    int s0 = bbase[b], e0 = bbase[b + 1];
    int rows0 = b << BSH;
    int nrows = min(512, NNODES - rows0);

    rcnt[t] = 0; rcnt[t + 256] = 0;
    __syncthreads();
    for (int j = s0 + t; j < e0; j += 256)
        atomicAdd(&rcnt[(unsigned)ebuf[j].x >> 18], 1);
    __syncthreads();

    int a0 = rcnt[2 * t], a1 = rcnt[2 * t + 1];
    s[t] = a0 + a1;
    __syncthreads();
    for (int off = 1; off < 256; off <<= 1) {
        int add = (t >= off) ? s[t - off] : 0;
        __syncthreads();
        s[t] += add;
        __syncthreads();
    }
    int pbase = s[t] - (a0 + a1);
    rbase[2 * t]     = pbase;
    rbase[2 * t + 1] = pbase + a0;
    __syncthreads();

    if (t < nrows)           rs[rows0 + t]       = s0 + rbase[t];
    if (t + 256 < nrows)     rs[rows0 + t + 256] = s0 + rbase[t + 256];

    rcnt[t] = rbase[t]; rcnt[t + 256] = rbase[t + 256];
    __syncthreads();

    for (int j = s0 + t; j < e0; j += 256) {
        int2 ee = ebuf[j];
        int lr  = (unsigned)ee.x >> 18;
        int pos = s0 + atomicAdd(&rcnt[lr], 1);
        cedge[pos] = make_int2(ee.x & 0x3FFFF, ee.y);
    }
}

// ---- dense init: h0(bf16) = all_emb; esum(fp32, = d_out) = all_emb ------

__global__ void init_k(const float4* __restrict__ ue, const float4* __restrict__ ie,
                       ushort4* __restrict__ h0, float4* __restrict__ esum) {
    int i = blockIdx.x * 256 + threadIdx.x;
    const int NU4 = NUSERS * (DIM / 4);
    const int NT4 = NNODES * (DIM / 4);
    if (i < NT4) {
        float4 v = (i < NU4) ? ue[i] : ie[i - NU4];
        esum[i] = v;
        ushort4 b;
        b.x = f2b(v.x); b.y = f2b(v.y); b.z = f2b(v.z); b.w = f2b(v.w);
        h0[i] = b;
    }
}

// ---- SpMM: one wave per row, lane = dim; 8-wide unrolled gather ---------

template <int FINAL>
__global__ void spmm_k(const int* __restrict__ rs, const int2* __restrict__ cedge,
                       const unsigned short* __restrict__ x,
                       unsigned short* __restrict__ hout, float* __restrict__ esum) {
    int w    = (blockIdx.x * blockDim.x + threadIdx.x) >> 6;
    int lane = threadIdx.x & 63;
    if (w >= NNODES) return;
    int s = rs[w], e = rs[w + 1];
    float acc = 0.f;
    int j = s;
    // 8 independent 128B gathers in flight per wave
    for (; j + 8 <= e; j += 8) {
        int2 e0 = cedge[j],     e1 = cedge[j + 1];
        int2 e2 = cedge[j + 2], e3 = cedge[j + 3];
        int2 e4 = cedge[j + 4], e5 = cedge[j + 5];
        int2 e6 = cedge[j + 6], e7 = cedge[j + 7];
        float x0 = b2f(x[e0.x * DIM + lane]);
        float x1 = b2f(x[e1.x * DIM + lane]);
        float x2 = b2f(x[e2.x * DIM + lane]);
        float x3 = b2f(x[e3.x * DIM + lane]);
        float x4 = b2f(x[e4.x * DIM + lane]);
        float x5 = b2f(x[e5.x * DIM + lane]);
        float x6 = b2f(x[e6.x * DIM + lane]);
        float x7 = b2f(x[e7.x * DIM + lane]);
        acc = fmaf(__int_as_float(e0.y), x0, acc);
        acc = fmaf(__int_as_float(e1.y), x1, acc);
        acc = fmaf(__int_as_float(e2.y), x2, acc);
        acc = fmaf(__int_as_float(e3.y), x3, acc);
        acc = fmaf(__int_as_float(e4.y), x4, acc);
        acc = fmaf(__int_as_float(e5.y), x5, acc);
        acc = fmaf(__int_as_float(e6.y), x6, acc);
        acc = fmaf(__int_as_float(e7.y), x7, acc);
    }
    for (; j < e; ++j) {
        int2 ee = cedge[j];
        acc = fmaf(__int_as_float(ee.y), b2f(x[ee.x * DIM + lane]), acc);
    }

    int o = w * DIM + lane;
    float r = esum[o] + acc;
    if (FINAL) {
        esum[o] = r * 0.25f;   // esum IS d_out
    } else {
        esum[o] = r;
        hout[o] = f2b(acc);
    }
}

// ---- launch -------------------------------------------------------------

extern "C" void kernel_launch(void* const* d_in, const int* in_sizes, int n_in,
                              void* d_out, int out_size, void* d_ws, size_t ws_size,
                              hipStream_t stream) {
    const float* ue   = (const float*)d_in[0];
    const float* ie   = (const float*)d_in[1];
    const float* vals = (const float*)d_in[2];
    const int*   rows = (const int*)d_in[3];
    const int*   cols = (const int*)d_in[4];
    float*       out  = (float*)d_out;

    char*  ws  = (char*)d_ws;
    size_t off = 0;
    auto alloc = [&](size_t bytes) -> char* {
        char* p = ws + off;
        off += (bytes + 255) & ~size_t(255);
        return p;
    };
    unsigned short* h0 = (unsigned short*)alloc((size_t)NNODES * DIM * 2);  // 19.2 MB
    unsigned short* h1 = (unsigned short*)alloc((size_t)NNODES * DIM * 2);  // 19.2 MB
    int2*  cedge  = (int2*)alloc((size_t)NNZ_E * 8);                        // 32 MB
    int2*  ebuf   = (int2*)alloc((size_t)NNZ_E * 8);                        // 32 MB
    int*   rs     = (int*)alloc((size_t)(NNODES + 1) * 4);
    int*   bcnt   = (int*)alloc((size_t)(NBKT + 1) * 4);
    int*   bbase  = (int*)alloc((size_t)(NBKT + 1) * 4);
    int*   bcur   = (int*)alloc((size_t)(NBKT + 1) * 4);
    (void)in_sizes; (void)n_in; (void)out_size;

    if (ws_size < off) return;   // clean absmax fail, not OOB fault

    // CSR build: LDS-aggregated multisplit
    hipMemsetAsync(bcnt, 0, (size_t)(NBKT + 1) * 4, stream);
    bhist_k<<<256, 256, 0, stream>>>(rows, bcnt);
    bscan_k<<<1, 512, 0, stream>>>(bcnt, bbase, bcur, rs);
    pass1_k<<<NB1, 256, 0, stream>>>(rows, cols, vals, bcur, ebuf);
    passC_k<<<NBKT, 256, 0, stream>>>(bbase, ebuf, rs, cedge);

    // dense init
    init_k<<<(NNODES * (DIM / 4) + 255) / 256, 256, 0, stream>>>(
        (const float4*)ue, (const float4*)ie, (ushort4*)h0, (float4*)out);

    // 3 propagation layers, emb_sum fused; last fuses /4
    const int SG = (NNODES * 64) / 256;
    spmm_k<0><<<SG, 256, 0, stream>>>(rs, cedge, h0, h1, out);
    spmm_k<0><<<SG, 256, 0, stream>>>(rs, cedge, h1, h0, out);
    spmm_k<1><<<SG, 256, 0, stream>>>(rs, cedge, h0, h1, out);
}

// Round 13
// 554.763 us; speedup vs baseline: 3.3780x; 1.2231x over previous
//
#include <hip/hip_runtime.h>
#include <hip/hip_bf16.h>

// LightGCN on MI355X: 3x SpMM + running sum. N=150000, DIM=64, NNZ=4M.
// R5:  fill_k 281us (random 4B scatter, 370MB write churn).
// R7:  int2 pack: WRITE->247MB but dur FLAT -> random-line-op bound.
//      bf16 h: spmm only -8% (2 lines/edge regardless of dtype).
// R9:  586-counter passB = 1102us: 6830-deep contended atomic chains.
// R10: LDS multisplit: 1874->840us. pass1 grid-starved (5% occ).
// R11: pass1 CHUNK->8192 (off top-5); spmm unroll 4->8: 190->135us
//      -> CONFIRMED latency/issue-bound (HBM 29%, VALU 32%, occ 75%).
// R12: spmm = 2 rows/wave, packed-uint gather: lanes 0-31 row 2w,
//      lanes 32-63 row 2w+1, each lane loads uint (2 bf16 dims).
//      Load instrs/edge halved, 16 edges in flight/wave. Same per-row
//      fma order -> bit-identical output.

#define NUSERS 100000
#define NITEMS 50000
#define NNODES 150000
#define DIM    64
#define NNZ_E  4000000
#define BSH    9                          // bucket = row >> 9 (512 rows)
#define NBKT   ((NNODES + 511) / 512)     // 293
#define CHUNK  8192                       // edges per pass1 block
#define NB1    ((NNZ_E + CHUNK - 1) / CHUNK)  // 489

__device__ inline unsigned short f2b(float f) {
    __hip_bfloat16 h = __float2bfloat16(f);
    return *reinterpret_cast<unsigned short*>(&h);
}
__device__ inline float b2f(unsigned short b) {
    return __uint_as_float((unsigned)b << 16);
}

// ---- bucket histogram (LDS-aggregated) ----------------------------------

__global__ void bhist_k(const int* __restrict__ rows, int* __restrict__ bcnt) {
    __shared__ int cnt[NBKT];
    for (int i = threadIdx.x; i < NBKT; i += 256) cnt[i] = 0;
    __syncthreads();
    int stride = gridDim.x * 256;
    for (int i = blockIdx.x * 256 + threadIdx.x; i < NNZ_E; i += stride)
        atomicAdd(&cnt[rows[i] >> BSH], 1);
    __syncthreads();
    for (int i = threadIdx.x; i < NBKT; i += 256)
        if (cnt[i]) atomicAdd(&bcnt[i], cnt[i]);
}

// ---- exclusive scan of 293 bucket counts (1 block of 512) ---------------

__global__ void bscan_k(const int* __restrict__ bcnt, int* __restrict__ bbase,
                        int* __restrict__ bcur, int* __restrict__ rs) {
    __shared__ int s[512];
    int t = threadIdx.x;
    int v = (t < NBKT) ? bcnt[t] : 0;
    s[t] = v;
    __syncthreads();
    for (int off = 1; off < 512; off <<= 1) {
        int add = (t >= off) ? s[t - off] : 0;
        __syncthreads();
        s[t] += add;
        __syncthreads();
    }
    if (t < NBKT) {
        int ex = s[t] - v;
        bbase[t] = ex;
        bcur[t]  = ex;
    }
    if (t == 0) {
        bbase[NBKT] = NNZ_E;
        rs[NNODES]  = NNZ_E;
    }
}

// ---- pass1: multisplit scatter into bucket-grouped ebuf -----------------

__global__ void pass1_k(const int* __restrict__ rows, const int* __restrict__ cols,
                        const float* __restrict__ vals, int* __restrict__ bcur,
                        int2* __restrict__ ebuf) {
    __shared__ int lcnt[NBKT];
    __shared__ int lcur[NBKT];
    int base = blockIdx.x * CHUNK;
    int end  = min(base + CHUNK, NNZ_E);
    for (int i = threadIdx.x; i < NBKT; i += 256) lcnt[i] = 0;
    __syncthreads();
    for (int i = base + threadIdx.x; i < end; i += 256)
        atomicAdd(&lcnt[rows[i] >> BSH], 1);
    __syncthreads();
    for (int i = threadIdx.x; i < NBKT; i += 256)
        lcur[i] = lcnt[i] ? atomicAdd(&bcur[i], lcnt[i]) : 0;
    __syncthreads();
    for (int i = base + threadIdx.x; i < end; i += 256) {
        int r = rows[i];
        int p = atomicAdd(&lcur[r >> BSH], 1);
        ebuf[p] = make_int2(cols[i] | ((r & 511) << 18), __float_as_int(vals[i]));
    }
}

// ---- passC: per-bucket LDS ranking -> exact CSR slots + rs --------------

__global__ void passC_k(const int* __restrict__ bbase, const int2* __restrict__ ebuf,
                        int* __restrict__ rs, int2* __restrict__ cedge) {
    __shared__ int rcnt[512];
    __shared__ int rbase[512];
    __shared__ int s[256];
    int b  = blockIdx.x;
    int t  = threadIdx.x;
    int s0 = bbase[b], e0 = bbase[b + 1];
    int rows0 = b << BSH;
    int nrows = min(512, NNODES - rows0);

    rcnt[t] = 0; rcnt[t + 256] = 0;
    __syncthreads();
    for (int j = s0 + t; j < e0; j += 256)
        atomicAdd(&rcnt[(unsigned)ebuf[j].x >> 18], 1);
    __syncthreads();

    int a0 = rcnt[2 * t], a1 = rcnt[2 * t + 1];
    s[t] = a0 + a1;
    __syncthreads();
    for (int off = 1; off < 256; off <<= 1) {
        int add = (t >= off) ? s[t - off] : 0;
        __syncthreads();
        s[t] += add;
        __syncthreads();
    }
    int pbase = s[t] - (a0 + a1);
    rbase[2 * t]     = pbase;
    rbase[2 * t + 1] = pbase + a0;
    __syncthreads();

    if (t < nrows)           rs[rows0 + t]       = s0 + rbase[t];
    if (t + 256 < nrows)     rs[rows0 + t + 256] = s0 + rbase[t + 256];

    rcnt[t] = rbase[t]; rcnt[t + 256] = rbase[t + 256];
    __syncthreads();

    for (int j = s0 + t; j < e0; j += 256) {
        int2 ee = ebuf[j];
        int lr  = (unsigned)ee.x >> 18;
        int pos = s0 + atomicAdd(&rcnt[lr], 1);
        cedge[pos] = make_int2(ee.x & 0x3FFFF, ee.y);
    }
}

// ---- dense init: h0(bf16) = all_emb; esum(fp32, = d_out) = all_emb ------

__global__ void init_k(const float4* __restrict__ ue, const float4* __restrict__ ie,
                       ushort4* __restrict__ h0, float4* __restrict__ esum) {
    int i = blockIdx.x * 256 + threadIdx.x;
    const int NU4 = NUSERS * (DIM / 4);
    const int NT4 = NNODES * (DIM / 4);
    if (i < NT4) {
        float4 v = (i < NU4) ? ue[i] : ie[i - NU4];
        esum[i] = v;
        ushort4 b;
        b.x = f2b(v.x); b.y = f2b(v.y); b.z = f2b(v.z); b.w = f2b(v.w);
        h0[i] = b;
    }
}

// ---- SpMM: 2 rows per wave; lane = (half, dim-pair); uint gathers -------
// half h=lane>>5 owns row 2w+h; lane loads uint = dims {2m, 2m+1} (m=lane&31).
// 8-deep unroll x 2 halves = 16 edges in flight per wave, 1 load instr/edge.

template <int FINAL>
__global__ void spmm_k(const int* __restrict__ rs, const int2* __restrict__ cedge,
                       const unsigned short* __restrict__ x,
                       unsigned short* __restrict__ hout, float* __restrict__ esum) {
    int pair = (blockIdx.x * blockDim.x + threadIdx.x) >> 6;  // wave id
    int lane = threadIdx.x & 63;
    int half = lane >> 5;
    int m    = lane & 31;                 // dim-pair: dims 2m, 2m+1
    int row  = pair * 2 + half;
    if (row >= NNODES) return;
    int s = rs[row], e = rs[row + 1];
    const char* xb = (const char*)x;

    float acc0 = 0.f, acc1 = 0.f;
    int j = s;
    for (; j + 8 <= e; j += 8) {
        int2 e0 = cedge[j],     e1 = cedge[j + 1];
        int2 e2 = cedge[j + 2], e3 = cedge[j + 3];
        int2 e4 = cedge[j + 4], e5 = cedge[j + 5];
        int2 e6 = cedge[j + 6], e7 = cedge[j + 7];
        unsigned u0 = *(const unsigned*)(xb + ((size_t)e0.x << 7) + (m << 2));
        unsigned u1 = *(const unsigned*)(xb + ((size_t)e1.x << 7) + (m << 2));
        unsigned u2 = *(const unsigned*)(xb + ((size_t)e2.x << 7) + (m << 2));
        unsigned u3 = *(const unsigned*)(xb + ((size_t)e3.x << 7) + (m << 2));
        unsigned u4 = *(const unsigned*)(xb + ((size_t)e4.x << 7) + (m << 2));
        unsigned u5 = *(const unsigned*)(xb + ((size_t)e5.x << 7) + (m << 2));
        unsigned u6 = *(const unsigned*)(xb + ((size_t)e6.x << 7) + (m << 2));
        unsigned u7 = *(const unsigned*)(xb + ((size_t)e7.x << 7) + (m << 2));
        float v0 = __int_as_float(e0.y), v1 = __int_as_float(e1.y);
        float v2 = __int_as_float(e2.y), v3 = __int_as_float(e3.y);
        float v4 = __int_as_float(e4.y), v5 = __int_as_float(e5.y);
        float v6 = __int_as_float(e6.y), v7 = __int_as_float(e7.y);
        acc0 = fmaf(v0, __uint_as_float(u0 << 16), acc0);
        acc1 = fmaf(v0, __uint_as_float(u0 & 0xffff0000u), acc1);
        acc0 = fmaf(v1, __uint_as_float(u1 << 16), acc0);
        acc1 = fmaf(v1, __uint_as_float(u1 & 0xffff0000u), acc1);
        acc0 = fmaf(v2, __uint_as_float(u2 << 16), acc0);
        acc1 = fmaf(v2, __uint_as_float(u2 & 0xffff0000u), acc1);
        acc0 = fmaf(v3, __uint_as_float(u3 << 16), acc0);
        acc1 = fmaf(v3, __uint_as_float(u3 & 0xffff0000u), acc1);
        acc0 = fmaf(v4, __uint_as_float(u4 << 16), acc0);
        acc1 = fmaf(v4, __uint_as_float(u4 & 0xffff0000u), acc1);
        acc0 = fmaf(v5, __uint_as_float(u5 << 16), acc0);
        acc1 = fmaf(v5, __uint_as_float(u5 & 0xffff0000u), acc1);
        acc0 = fmaf(v6, __uint_as_float(u6 << 16), acc0);
        acc1 = fmaf(v6, __uint_as_float(u6 & 0xffff0000u), acc1);
        acc0 = fmaf(v7, __uint_as_float(u7 << 16), acc0);
        acc1 = fmaf(v7, __uint_as_float(u7 & 0xffff0000u), acc1);
    }
    for (; j < e; ++j) {
        int2 ee = cedge[j];
        unsigned u = *(const unsigned*)(xb + ((size_t)ee.x << 7) + (m << 2));
        float v = __int_as_float(ee.y);
        acc0 = fmaf(v, __uint_as_float(u << 16), acc0);
        acc1 = fmaf(v, __uint_as_float(u & 0xffff0000u), acc1);
    }

    int o2 = row * 32 + m;                        // float2 / uint index
    float2 rv = ((const float2*)esum)[o2];
    float r0 = rv.x + acc0, r1 = rv.y + acc1;
    if (FINAL) {
        ((float2*)esum)[o2] = make_float2(r0 * 0.25f, r1 * 0.25f);
    } else {
        ((float2*)esum)[o2] = make_float2(r0, r1);
        ((unsigned*)hout)[o2] = ((unsigned)f2b(acc1) << 16) | f2b(acc0);
    }
}

// ---- launch -------------------------------------------------------------

extern "C" void kernel_launch(void* const* d_in, const int* in_sizes, int n_in,
                              void* d_out, int out_size, void* d_ws, size_t ws_size,
                              hipStream_t stream) {
    const float* ue   = (const float*)d_in[0];
    const float* ie   = (const float*)d_in[1];
    const float* vals = (const float*)d_in[2];
    const int*   rows = (const int*)d_in[3];
    const int*   cols = (const int*)d_in[4];
    float*       out  = (float*)d_out;

    char*  ws  = (char*)d_ws;
    size_t off = 0;
    auto alloc = [&](size_t bytes) -> char* {
        char* p = ws + off;
        off += (bytes + 255) & ~size_t(255);
        return p;
    };
    unsigned short* h0 = (unsigned short*)alloc((size_t)NNODES * DIM * 2);  // 19.2 MB
    unsigned short* h1 = (unsigned short*)alloc((size_t)NNODES * DIM * 2);  // 19.2 MB
    int2*  cedge  = (int2*)alloc((size_t)NNZ_E * 8);                        // 32 MB
    int2*  ebuf   = (int2*)alloc((size_t)NNZ_E * 8);                        // 32 MB
    int*   rs     = (int*)alloc((size_t)(NNODES + 1) * 4);
    int*   bcnt   = (int*)alloc((size_t)(NBKT + 1) * 4);
    int*   bbase  = (int*)alloc((size_t)(NBKT + 1) * 4);
    int*   bcur   = (int*)alloc((size_t)(NBKT + 1) * 4);
    (void)in_sizes; (void)n_in; (void)out_size;

    if (ws_size < off) return;   // clean absmax fail, not OOB fault

    // CSR build: LDS-aggregated multisplit
    hipMemsetAsync(bcnt, 0, (size_t)(NBKT + 1) * 4, stream);
    bhist_k<<<256, 256, 0, stream>>>(rows, bcnt);
    bscan_k<<<1, 512, 0, stream>>>(bcnt, bbase, bcur, rs);
    pass1_k<<<NB1, 256, 0, stream>>>(rows, cols, vals, bcur, ebuf);
    passC_k<<<NBKT, 256, 0, stream>>>(bbase, ebuf, rs, cedge);

    // dense init
    init_k<<<(NNODES * (DIM / 4) + 255) / 256, 256, 0, stream>>>(
        (const float4*)ue, (const float4*)ie, (ushort4*)h0, (float4*)out);

    // 3 propagation layers, emb_sum fused; last fuses /4
    // 2 rows/wave -> 75000 waves -> 18750 blocks of 256
    const int SG = (NNODES / 2) * 64 / 256;
    spmm_k<0><<<SG, 256, 0, stream>>>(rs, cedge, h0, h1, out);
    spmm_k<0><<<SG, 256, 0, stream>>>(rs, cedge, h1, h0, out);
    spmm_k<1><<<SG, 256, 0, stream>>>(rs, cedge, h0, h1, out);
}